// Round 2
// baseline (202.052 us; speedup 1.0000x reference)
//
#include <hip/hip_runtime.h>
#include <hip/hip_bf16.h>

// GeometricFlow: one block per batch element, 256 threads.
// Phases: metric MLP -> christoffel (512 triples, shared-base trick) ->
//         ricci (64 pairs, shared-base trick) -> flow MLP -> out.
// All tensors are float32 (reference dtype); compute in fp32.

#define MDIM 8
#define HIDC 128   // christoffel / metric / flow hidden
#define HIDR 256   // ricci hidden

__global__ __launch_bounds__(256, 4) void geoflow_kernel(
    const float* __restrict__ points,
    const float* __restrict__ Wm1, const float* __restrict__ bm1,
    const float* __restrict__ Wm2, const float* __restrict__ bm2,
    const float* __restrict__ Wc1, const float* __restrict__ bc1,
    const float* __restrict__ Wc2, const float* __restrict__ bc2,
    const float* __restrict__ Wr1, const float* __restrict__ br1,
    const float* __restrict__ Wr2, const float* __restrict__ br2,
    const float* __restrict__ Wf1, const float* __restrict__ bf1v,
    const float* __restrict__ Wf2, const float* __restrict__ bf2v,
    float* __restrict__ outp)
{
    __shared__ float  p[MDIM];
    __shared__ float  hm[HIDC];        // metric hidden (post-relu)
    __shared__ float  g[64];           // metric tensor (row-major i*8+j)
    __shared__ float4 c4[HIDC];        // {base, w_gij, w_gjk, w_gki} per christoffel unit
    __shared__ float  wc2s[HIDC];      // christoffel output weights
    __shared__ float  chris[512];      // chris[i*64 + j*8 + k]
    __shared__ float4 r4a[HIDR];       // {base2, w_g, w_c0, w_c1}
    __shared__ float4 r4b[HIDR];       // {w_c2..w_c5}
    __shared__ float4 r4c[HIDR];       // {w_c6, w_c7, wr2, 0}
    __shared__ float  ric[64];
    __shared__ float  flowin[2 * MDIM];
    __shared__ float  fh[HIDC];

    const int b   = blockIdx.x;
    const int tid = threadIdx.x;

    if (tid < MDIM) p[tid] = points[b * MDIM + tid];
    __syncthreads();

    // ---- phase 2: lower half -> metric hidden; upper half -> christoffel prep ----
    if (tid < 128) {
        float acc = bm1[tid];
        #pragma unroll
        for (int d = 0; d < MDIM; ++d) acc += p[d] * Wm1[d * 128 + tid];
        hm[tid] = fmaxf(acc, 0.f);
    } else {
        const int h = tid - 128;
        float base = bc1[h];
        #pragma unroll
        for (int d = 0; d < MDIM; ++d) base += p[d] * Wc1[d * 128 + h];
        c4[h] = make_float4(base,
                            Wc1[8 * 128 + h],
                            Wc1[9 * 128 + h],
                            Wc1[10 * 128 + h]);
        wc2s[h] = Wc2[h];
    }
    __syncthreads();

    // ---- phase 3: all threads -> ricci prep (unit tid); tid<64 also metric out g ----
    {
        const int h = tid;
        float base2 = br1[h];
        #pragma unroll
        for (int d = 0; d < MDIM; ++d) base2 += p[d] * Wr1[d * HIDR + h];
        r4a[h] = make_float4(base2,
                             Wr1[8 * HIDR + h],
                             Wr1[9 * HIDR + h],
                             Wr1[10 * HIDR + h]);
        r4b[h] = make_float4(Wr1[11 * HIDR + h],
                             Wr1[12 * HIDR + h],
                             Wr1[13 * HIDR + h],
                             Wr1[14 * HIDR + h]);
        r4c[h] = make_float4(Wr1[15 * HIDR + h],
                             Wr1[16 * HIDR + h],
                             Wr2[h], 0.f);
    }
    if (tid < 64) {
        float acc = bm2[tid];
        for (int h = 0; h < 128; ++h) acc += hm[h] * Wm2[h * 64 + tid];
        g[tid] = acc;
    }
    __syncthreads();

    // ---- phase 4: christoffel, 2 triples per thread ----
    const float bc2f = bc2[0];
    #pragma unroll
    for (int rep = 0; rep < 2; ++rep) {
        const int t = tid + rep * 256;          // triple = i*64 + j*8 + k
        const int i = t >> 6, j = (t >> 3) & 7, k = t & 7;
        const float gij = g[i * 8 + j];
        const float gjk = g[j * 8 + k];
        const float gki = g[k * 8 + i];
        float acc = 0.f;
        #pragma unroll 4
        for (int h = 0; h < HIDC; ++h) {
            const float4 c = c4[h];
            const float x = c.x + gij * c.y + gjk * c.z + gki * c.w;
            // tanh(x) = 1 - 2/(exp(2x)+1), native exp + rcp
            const float e  = __expf(x + x);
            const float th = 1.f - 2.f * __builtin_amdgcn_rcpf(e + 1.f);
            acc += th * wc2s[h];
        }
        chris[t] = acc + bc2f;
    }
    __syncthreads();

    // ---- phase 5: ricci, 4 threads per (i,j) pair, interleaved hidden units ----
    {
        const int pair = tid >> 2;   // i*8 + j
        const int part = tid & 3;
        const float gij = g[pair];
        float ch[8];
        #pragma unroll
        for (int k = 0; k < 8; ++k) ch[k] = chris[pair * 8 + k];
        float acc = 0.f;
        #pragma unroll 4
        for (int idx = 0; idx < 64; ++idx) {
            const int h = (idx << 2) | part;   // lanes 0..3 read consecutive float4s
            const float4 a  = r4a[h];
            const float4 bq = r4b[h];
            const float4 c  = r4c[h];
            float x = a.x + gij * a.y + ch[0] * a.z + ch[1] * a.w
                    + ch[2] * bq.x + ch[3] * bq.y + ch[4] * bq.z + ch[5] * bq.w
                    + ch[6] * c.x + ch[7] * c.y;
            x = fmaxf(x, 0.f);
            acc += x * c.z;
        }
        acc += __shfl_xor(acc, 1);
        acc += __shfl_xor(acc, 2);
        if (part == 0) ric[pair] = acc + br2[0];
    }
    __syncthreads();

    // ---- phase 6: ric . p, build flow input ----
    if (tid < MDIM) {
        float rp = 0.f;
        #pragma unroll
        for (int j = 0; j < MDIM; ++j) rp += ric[tid * 8 + j] * p[j];
        flowin[tid]        = p[tid];
        flowin[MDIM + tid] = rp;
    }
    __syncthreads();

    // ---- phase 7: flow hidden ----
    if (tid < 128) {
        float acc = bf1v[tid];
        #pragma unroll
        for (int d = 0; d < 2 * MDIM; ++d) acc += flowin[d] * Wf1[d * 128 + tid];
        fh[tid] = fmaxf(acc, 0.f);
    }
    __syncthreads();

    // ---- phase 8: flow out + final update ----
    if (tid < MDIM) {
        float acc = bf2v[tid];
        for (int h = 0; h < 128; ++h) acc += fh[h] * Wf2[h * 8 + tid];
        outp[b * MDIM + tid] = p[tid] + 0.01f * acc;
    }
}

extern "C" void kernel_launch(void* const* d_in, const int* in_sizes, int n_in,
                              void* d_out, int out_size, void* d_ws, size_t ws_size,
                              hipStream_t stream) {
    const float* points = (const float*)d_in[0];
    const float* Wm1 = (const float*)d_in[1];
    const float* bm1 = (const float*)d_in[2];
    const float* Wm2 = (const float*)d_in[3];
    const float* bm2 = (const float*)d_in[4];
    const float* Wc1 = (const float*)d_in[5];
    const float* bc1 = (const float*)d_in[6];
    const float* Wc2 = (const float*)d_in[7];
    const float* bc2 = (const float*)d_in[8];
    const float* Wr1 = (const float*)d_in[9];
    const float* br1 = (const float*)d_in[10];
    const float* Wr2 = (const float*)d_in[11];
    const float* br2 = (const float*)d_in[12];
    const float* Wf1 = (const float*)d_in[13];
    const float* bf1v = (const float*)d_in[14];
    const float* Wf2 = (const float*)d_in[15];
    const float* bf2v = (const float*)d_in[16];
    float* outp = (float*)d_out;

    const int BATCH = in_sizes[0] / MDIM;   // 4096
    geoflow_kernel<<<BATCH, 256, 0, stream>>>(
        points, Wm1, bm1, Wm2, bm2, Wc1, bc1, Wc2, bc2,
        Wr1, br1, Wr2, br2, Wf1, bf1v, Wf2, bf2v, outp);
}

// Round 3
// 194.215 us; speedup vs baseline: 1.0404x; 1.0404x over previous
//
#include <hip/hip_runtime.h>
#include <hip/hip_bf16.h>

// GeometricFlow: one block per batch element, 256 threads.
// Phases: metric MLP -> christoffel (512 triples, shared-base trick) ->
//         ricci (64 pairs, shared-base trick) -> flow MLP -> out.
// All tensors are float32 (reference dtype); compute in fp32.
//
// Round-3 change: christoffel tanh via native v_exp_f32 (exp2 builtin) with
// the -2/ln2 scale folded into the stage-1 weights at prep time, and the
// constant sum (bc2 + sum(Wc2)) hoisted out of the inner loop:
//   tanh(x) = 1 - 2e/(1+e), e = e^{-2x} = exp2(t), t = (-2/ln2)*x
//   chris   = [bc2 + sum(w)] + sum_h (-2 w_h) * e_h * rcp(1 + e_h)

#define MDIM 8
#define HIDC 128   // christoffel / metric / flow hidden
#define HIDR 256   // ricci hidden

#define NEG2_OVER_LN2 (-2.885390081777927f)   // -2/ln(2) = -2*log2(e)

__global__ __launch_bounds__(256, 4) void geoflow_kernel(
    const float* __restrict__ points,
    const float* __restrict__ Wm1, const float* __restrict__ bm1,
    const float* __restrict__ Wm2, const float* __restrict__ bm2,
    const float* __restrict__ Wc1, const float* __restrict__ bc1,
    const float* __restrict__ Wc2, const float* __restrict__ bc2,
    const float* __restrict__ Wr1, const float* __restrict__ br1,
    const float* __restrict__ Wr2, const float* __restrict__ br2,
    const float* __restrict__ Wf1, const float* __restrict__ bf1v,
    const float* __restrict__ Wf2, const float* __restrict__ bf2v,
    float* __restrict__ outp)
{
    __shared__ float  p[MDIM];
    __shared__ float  hm[HIDC];        // metric hidden (post-relu)
    __shared__ float  g[64];           // metric tensor (row-major i*8+j)
    __shared__ float4 c4[HIDC];        // scaled {base, w_gij, w_gjk, w_gki}
    __shared__ float  wc2s[HIDC];      // -2 * Wc2
    __shared__ float  chris[512];      // chris[i*64 + j*8 + k]
    __shared__ float4 r4a[HIDR];       // {base2, w_g, w_c0, w_c1}
    __shared__ float4 r4b[HIDR];       // {w_c2..w_c5}
    __shared__ float4 r4c[HIDR];       // {w_c6, w_c7, wr2, 0}
    __shared__ float  ric[64];
    __shared__ float  flowin[2 * MDIM];
    __shared__ float  fh[HIDC];
    __shared__ float  chrisBias;       // bc2 + sum_h Wc2[h]

    const int b   = blockIdx.x;
    const int tid = threadIdx.x;

    if (tid < MDIM) p[tid] = points[b * MDIM + tid];
    __syncthreads();

    // ---- phase 2: lower half -> metric hidden; upper half -> christoffel prep ----
    if (tid < 128) {
        float acc = bm1[tid];
        #pragma unroll
        for (int d = 0; d < MDIM; ++d) acc += p[d] * Wm1[d * 128 + tid];
        hm[tid] = fmaxf(acc, 0.f);
    } else {
        const int h = tid - 128;
        float base = bc1[h];
        #pragma unroll
        for (int d = 0; d < MDIM; ++d) base += p[d] * Wc1[d * 128 + h];
        c4[h] = make_float4(NEG2_OVER_LN2 * base,
                            NEG2_OVER_LN2 * Wc1[8 * 128 + h],
                            NEG2_OVER_LN2 * Wc1[9 * 128 + h],
                            NEG2_OVER_LN2 * Wc1[10 * 128 + h]);
        wc2s[h] = -2.f * Wc2[h];
    }
    __syncthreads();

    // ---- phase 3: all threads -> ricci prep (unit tid); tid<64 also metric out g ----
    {
        const int h = tid;
        float base2 = br1[h];
        #pragma unroll
        for (int d = 0; d < MDIM; ++d) base2 += p[d] * Wr1[d * HIDR + h];
        r4a[h] = make_float4(base2,
                             Wr1[8 * HIDR + h],
                             Wr1[9 * HIDR + h],
                             Wr1[10 * HIDR + h]);
        r4b[h] = make_float4(Wr1[11 * HIDR + h],
                             Wr1[12 * HIDR + h],
                             Wr1[13 * HIDR + h],
                             Wr1[14 * HIDR + h]);
        r4c[h] = make_float4(Wr1[15 * HIDR + h],
                             Wr1[16 * HIDR + h],
                             Wr2[h], 0.f);
    }
    if (tid < 64) {
        float acc = bm2[tid];
        for (int h = 0; h < 128; ++h) acc += hm[h] * Wm2[h * 64 + tid];
        g[tid] = acc;
    }
    if (tid == 255) {   // wc2s holds -2*Wc2 -> sum(Wc2) = -0.5 * sum(wc2s)
        float s = 0.f;
        for (int h = 0; h < HIDC; ++h) s += wc2s[h];
        chrisBias = bc2[0] - 0.5f * s;
    }
    __syncthreads();

    // ---- phase 4: christoffel, 2 triples per thread ----
    const float cb = chrisBias;
    #pragma unroll
    for (int rep = 0; rep < 2; ++rep) {
        const int t = tid + rep * 256;          // triple = i*64 + j*8 + k
        const int i = t >> 6, j = (t >> 3) & 7, k = t & 7;
        const float gij = g[i * 8 + j];
        const float gjk = g[j * 8 + k];
        const float gki = g[k * 8 + i];
        float acc = 0.f;
        #pragma unroll 4
        for (int h = 0; h < HIDC; ++h) {
            const float4 c = c4[h];
            float tt = c.x + gij * c.y + gjk * c.z + gki * c.w;  // (-2/ln2)*x
            tt = fminf(tt, 126.f);                               // avoid inf*0
            const float e = __builtin_amdgcn_exp2f(tt);          // e^{-2x}
            const float r = __builtin_amdgcn_rcpf(e + 1.f);
            acc += (wc2s[h] * e) * r;                            // (-2w)*e/(1+e)
        }
        chris[t] = acc + cb;
    }
    __syncthreads();

    // ---- phase 5: ricci, 4 threads per (i,j) pair, interleaved hidden units ----
    {
        const int pair = tid >> 2;   // i*8 + j
        const int part = tid & 3;
        const float gij = g[pair];
        float ch[8];
        #pragma unroll
        for (int k = 0; k < 8; ++k) ch[k] = chris[pair * 8 + k];
        float acc = 0.f;
        #pragma unroll 4
        for (int idx = 0; idx < 64; ++idx) {
            const int h = (idx << 2) | part;   // lanes 0..3 read consecutive float4s
            const float4 a  = r4a[h];
            const float4 bq = r4b[h];
            const float4 c  = r4c[h];
            float x = a.x + gij * a.y + ch[0] * a.z + ch[1] * a.w
                    + ch[2] * bq.x + ch[3] * bq.y + ch[4] * bq.z + ch[5] * bq.w
                    + ch[6] * c.x + ch[7] * c.y;
            x = fmaxf(x, 0.f);
            acc += x * c.z;
        }
        acc += __shfl_xor(acc, 1);
        acc += __shfl_xor(acc, 2);
        if (part == 0) ric[pair] = acc + br2[0];
    }
    __syncthreads();

    // ---- phase 6: ric . p, build flow input ----
    if (tid < MDIM) {
        float rp = 0.f;
        #pragma unroll
        for (int j = 0; j < MDIM; ++j) rp += ric[tid * 8 + j] * p[j];
        flowin[tid]        = p[tid];
        flowin[MDIM + tid] = rp;
    }
    __syncthreads();

    // ---- phase 7: flow hidden ----
    if (tid < 128) {
        float acc = bf1v[tid];
        #pragma unroll
        for (int d = 0; d < 2 * MDIM; ++d) acc += flowin[d] * Wf1[d * 128 + tid];
        fh[tid] = fmaxf(acc, 0.f);
    }
    __syncthreads();

    // ---- phase 8: flow out + final update ----
    if (tid < MDIM) {
        float acc = bf2v[tid];
        for (int h = 0; h < 128; ++h) acc += fh[h] * Wf2[h * 8 + tid];
        outp[b * MDIM + tid] = p[tid] + 0.01f * acc;
    }
}

extern "C" void kernel_launch(void* const* d_in, const int* in_sizes, int n_in,
                              void* d_out, int out_size, void* d_ws, size_t ws_size,
                              hipStream_t stream) {
    const float* points = (const float*)d_in[0];
    const float* Wm1 = (const float*)d_in[1];
    const float* bm1 = (const float*)d_in[2];
    const float* Wm2 = (const float*)d_in[3];
    const float* bm2 = (const float*)d_in[4];
    const float* Wc1 = (const float*)d_in[5];
    const float* bc1 = (const float*)d_in[6];
    const float* Wc2 = (const float*)d_in[7];
    const float* bc2 = (const float*)d_in[8];
    const float* Wr1 = (const float*)d_in[9];
    const float* br1 = (const float*)d_in[10];
    const float* Wr2 = (const float*)d_in[11];
    const float* br2 = (const float*)d_in[12];
    const float* Wf1 = (const float*)d_in[13];
    const float* bf1v = (const float*)d_in[14];
    const float* Wf2 = (const float*)d_in[15];
    const float* bf2v = (const float*)d_in[16];
    float* outp = (float*)d_out;

    const int BATCH = in_sizes[0] / MDIM;   // 4096
    geoflow_kernel<<<BATCH, 256, 0, stream>>>(
        points, Wm1, bm1, Wm2, bm2, Wc1, bc1, Wc2, bc2,
        Wr1, br1, Wr2, br2, Wf1, bf1v, Wf2, bf2v, outp);
}